// Round 3
// baseline (2491.169 us; speedup 1.0000x reference)
//
#include <hip/hip_runtime.h>
#include <hip/hip_bf16.h>
#include <hip/hip_cooperative_groups.h>

namespace cg = cooperative_groups;

#define VOCAB 50000
#define EMBD  512
#define HID   1024
#define NBATCH 256
#define SEQW  26
#define KTOT  (EMBD + HID)   /* 1536 */

typedef short short8 __attribute__((ext_vector_type(8)));
typedef float f32x4  __attribute__((ext_vector_type(4)));

__device__ __forceinline__ unsigned short f2bf_bits(float x) {
    union { __hip_bfloat16 b; unsigned short u; } cv;
    cv.b = __float2bfloat16(x);
    return cv.u;
}

__device__ __forceinline__ void split_bf16(float x, unsigned short& hi, unsigned short& lo) {
    __hip_bfloat16 h = __float2bfloat16(x);
    float hf = __bfloat162float(h);
    hi = f2bf_bits(x);
    lo = f2bf_bits(x - hf);
}

// ---------------- init: zero h0 (hi/lo) ----------------
__global__ void init_kernel(unsigned short* __restrict__ hHi0,
                            unsigned short* __restrict__ hLo0) {
    int idx = blockIdx.x * blockDim.x + threadIdx.x; // 65536 threads x4
    #pragma unroll
    for (int k = 0; k < 4; ++k) {
        hHi0[idx * 4 + k] = 0;
        hLo0[idx * 4 + k] = 0;
    }
}

// ---------------- embedding: gather + tanh -> bf16 hi/lo ----------------
__global__ void embed_kernel(const int* __restrict__ qv,
                             const float* __restrict__ Wemb,
                             unsigned short* __restrict__ eHi,
                             unsigned short* __restrict__ eLo) {
    int pair = blockIdx.x * 4 + (threadIdx.x >> 6);
    int t = pair / NBATCH;
    int b = pair % NBATCH;
    int tok = qv[b * SEQW + t];
    int lane = threadIdx.x & 63;
    size_t base = (size_t)pair * EMBD;
    if (tok > 0) {
        int v = tok - 1;
        for (int e = lane; e < EMBD; e += 64) {
            float x = Wemb[(size_t)e * VOCAB + v];
            float y = tanhf(x);
            unsigned short hi, lo;
            split_bf16(y, hi, lo);
            eHi[base + e] = hi;
            eLo[base + e] = lo;
        }
    } else {
        for (int e = lane; e < EMBD; e += 64) {
            eHi[base + e] = 0;
            eLo[base + e] = 0;
        }
    }
}

// ---------------- weight concat + bf16 split + bias sum ----------------
__global__ void convw_kernel(const float* __restrict__ Wih,
                             const float* __restrict__ Whh,
                             const float* __restrict__ b_ih,
                             const float* __restrict__ b_hh,
                             unsigned short* __restrict__ wHi,
                             unsigned short* __restrict__ wLo,
                             float* __restrict__ bsum) {
    int j = blockIdx.x; // 0..4095
    if (threadIdx.x == 0) bsum[j] = b_ih[j] + b_hh[j];
    for (int col = threadIdx.x; col < KTOT; col += blockDim.x) {
        float x = (col < EMBD) ? Wih[(size_t)j * EMBD + col]
                               : Whh[(size_t)j * HID + (col - EMBD)];
        unsigned short hi, lo;
        split_bf16(x, hi, lo);
        wHi[(size_t)j * KTOT + col] = hi;
        wLo[(size_t)j * KTOT + col] = lo;
    }
}

// ---------------- persistent LSTM: all 26 steps in one cooperative kernel ----
// 256 blocks x 512 threads (8 waves). Block bx:
//   jt = (bx%8)*8 + (bx/8)%8  (XCD-clustered: each XCD owns 8 jh-tiles ->
//        512 Wcat rows x 1536 x 4B(hi+lo) = 3.15MB, L2-resident across steps)
//   mt = bx/64  (batch tile of 64)
// Wave w = (gate g = w&3, mhalf mh = w>>2): 32x16 tile = 2 Mfrags x 1 Nfrag.
// c-state lives in registers (2 cells/thread) for all 26 steps.
__global__ __launch_bounds__(512, 2) void lstm_persist(
    const unsigned short* __restrict__ embHi, const unsigned short* __restrict__ embLo,
    unsigned short* __restrict__ h0Hi, unsigned short* __restrict__ h0Lo,
    unsigned short* __restrict__ h1Hi, unsigned short* __restrict__ h1Lo,
    const unsigned short* __restrict__ WHi, const unsigned short* __restrict__ WLo,
    const float* __restrict__ bsum,
    float* __restrict__ out)
{
    cg::grid_group grid = cg::this_grid();

    int bx = blockIdx.x;
    int jt = (bx & 7) * 8 + ((bx >> 3) & 7);   // 0..63
    int mt = bx >> 6;                          // 0..3
    int jh0 = jt * 16;
    int m0 = mt * 64;

    int tid = threadIdx.x;
    int wave = tid >> 6;
    int g   = wave & 3;
    int mh  = wave >> 2;
    int lane = tid & 63;
    int col16 = lane & 15;
    int g4 = lane >> 4;

    int mA = m0 + mh * 32 + col16;            // A row (fm=0); fm=1 adds 16
    int jB = g * HID + jh0 + col16;           // B row (Wcat)
    const unsigned short* bHiP = WHi + (size_t)jB * KTOT + 8 * g4;
    const unsigned short* bLoP = WLo + (size_t)jB * KTOT + 8 * g4;

    // per-thread epilogue cells: idx = tid + u*512 -> (ml=idx>>4, nl=idx&15)
    float bs[2][4];
    float cReg[2] = {0.0f, 0.0f};
    #pragma unroll
    for (int u = 0; u < 2; ++u) {
        int nl = (tid + u * 512) & 15;
        #pragma unroll
        for (int gg = 0; gg < 4; ++gg)
            bs[u][gg] = bsum[gg * HID + jh0 + nl];
    }

    __shared__ float gbuf[4][64][16];

    for (int t = 0; t < SEQW; ++t) {
        const unsigned short* hInHi  = (t & 1) ? h1Hi : h0Hi;
        const unsigned short* hInLo  = (t & 1) ? h1Lo : h0Lo;
        unsigned short*       hOutHi = (t & 1) ? h0Hi : h1Hi;
        unsigned short*       hOutLo = (t & 1) ? h0Lo : h1Lo;

        f32x4 acc0 = {0.f, 0.f, 0.f, 0.f};
        f32x4 acc1 = {0.f, 0.f, 0.f, 0.f};

        const unsigned short* e0Hi = embHi + ((size_t)t * NBATCH + mA) * EMBD + 8 * g4;
        const unsigned short* e0Lo = embLo + ((size_t)t * NBATCH + mA) * EMBD + 8 * g4;
        const unsigned short* e1Hi = e0Hi + (size_t)16 * EMBD;
        const unsigned short* e1Lo = e0Lo + (size_t)16 * EMBD;

        #pragma unroll
        for (int kk = 0; kk < EMBD; kk += 32) {
            short8 aH0 = *(const short8*)(e0Hi + kk);
            short8 aL0 = *(const short8*)(e0Lo + kk);
            short8 aH1 = *(const short8*)(e1Hi + kk);
            short8 aL1 = *(const short8*)(e1Lo + kk);
            short8 bH  = *(const short8*)(bHiP + kk);
            short8 bL  = *(const short8*)(bLoP + kk);
            acc0 = __builtin_amdgcn_mfma_f32_16x16x32_bf16(aH0, bH, acc0, 0, 0, 0);
            acc0 = __builtin_amdgcn_mfma_f32_16x16x32_bf16(aH0, bL, acc0, 0, 0, 0);
            acc0 = __builtin_amdgcn_mfma_f32_16x16x32_bf16(aL0, bH, acc0, 0, 0, 0);
            acc1 = __builtin_amdgcn_mfma_f32_16x16x32_bf16(aH1, bH, acc1, 0, 0, 0);
            acc1 = __builtin_amdgcn_mfma_f32_16x16x32_bf16(aH1, bL, acc1, 0, 0, 0);
            acc1 = __builtin_amdgcn_mfma_f32_16x16x32_bf16(aL1, bH, acc1, 0, 0, 0);
        }

        const unsigned short* f0Hi = hInHi + (size_t)mA * HID + 8 * g4;
        const unsigned short* f0Lo = hInLo + (size_t)mA * HID + 8 * g4;
        const unsigned short* f1Hi = f0Hi + (size_t)16 * HID;
        const unsigned short* f1Lo = f0Lo + (size_t)16 * HID;
        const unsigned short* bHiP2 = bHiP + EMBD;
        const unsigned short* bLoP2 = bLoP + EMBD;

        #pragma unroll
        for (int kk = 0; kk < HID; kk += 32) {
            short8 aH0 = *(const short8*)(f0Hi + kk);
            short8 aL0 = *(const short8*)(f0Lo + kk);
            short8 aH1 = *(const short8*)(f1Hi + kk);
            short8 aL1 = *(const short8*)(f1Lo + kk);
            short8 bH  = *(const short8*)(bHiP2 + kk);
            short8 bL  = *(const short8*)(bLoP2 + kk);
            acc0 = __builtin_amdgcn_mfma_f32_16x16x32_bf16(aH0, bH, acc0, 0, 0, 0);
            acc0 = __builtin_amdgcn_mfma_f32_16x16x32_bf16(aH0, bL, acc0, 0, 0, 0);
            acc0 = __builtin_amdgcn_mfma_f32_16x16x32_bf16(aL0, bH, acc0, 0, 0, 0);
            acc1 = __builtin_amdgcn_mfma_f32_16x16x32_bf16(aH1, bH, acc1, 0, 0, 0);
            acc1 = __builtin_amdgcn_mfma_f32_16x16x32_bf16(aH1, bL, acc1, 0, 0, 0);
            acc1 = __builtin_amdgcn_mfma_f32_16x16x32_bf16(aL1, bH, acc1, 0, 0, 0);
        }

        #pragma unroll
        for (int r = 0; r < 4; ++r) {
            gbuf[g][mh * 32 +      g4 * 4 + r][col16] = acc0[r];
            gbuf[g][mh * 32 + 16 + g4 * 4 + r][col16] = acc1[r];
        }
        __syncthreads();

        #pragma unroll
        for (int u = 0; u < 2; ++u) {
            int idx = tid + u * 512;
            int ml = idx >> 4, nl = idx & 15;
            int b = m0 + ml, jh = jh0 + nl;
            float gi  = gbuf[0][ml][nl] + bs[u][0];
            float gf  = gbuf[1][ml][nl] + bs[u][1];
            float gg_ = gbuf[2][ml][nl] + bs[u][2];
            float go  = gbuf[3][ml][nl] + bs[u][3];
            float si = 1.0f / (1.0f + expf(-gi));
            float sf = 1.0f / (1.0f + expf(-gf));
            float so = 1.0f / (1.0f + expf(-go));
            float tg = tanhf(gg_);
            float cN = sf * cReg[u] + si * tg;
            float hN = so * tanhf(cN);
            cReg[u] = cN;
            size_t p = (size_t)b * HID + jh;
            unsigned short hh, hl;
            split_bf16(hN, hh, hl);
            hOutHi[p] = hh;
            hOutLo[p] = hl;
            if (t == SEQW - 1) out[p] = hN;
        }

        grid.sync();
    }
}

extern "C" void kernel_launch(void* const* d_in, const int* in_sizes, int n_in,
                              void* d_out, int out_size, void* d_ws, size_t ws_size,
                              hipStream_t stream) {
    const int*   qv   = (const int*)d_in[0];
    const float* Wemb = (const float*)d_in[2];
    const float* Wih  = (const float*)d_in[3];
    const float* Whh  = (const float*)d_in[4];
    const float* b_ih = (const float*)d_in[5];
    const float* b_hh = (const float*)d_in[6];
    float* out = (float*)d_out;

    char* ws = (char*)d_ws;
    size_t off = 0;
    unsigned short* embHi = (unsigned short*)(ws + off); off += (size_t)SEQW * NBATCH * EMBD * 2;
    unsigned short* embLo = (unsigned short*)(ws + off); off += (size_t)SEQW * NBATCH * EMBD * 2;
    unsigned short* WHi   = (unsigned short*)(ws + off); off += (size_t)4 * HID * KTOT * 2;
    unsigned short* WLo   = (unsigned short*)(ws + off); off += (size_t)4 * HID * KTOT * 2;
    unsigned short* h0Hi  = (unsigned short*)(ws + off); off += (size_t)NBATCH * HID * 2;
    unsigned short* h0Lo  = (unsigned short*)(ws + off); off += (size_t)NBATCH * HID * 2;
    unsigned short* h1Hi  = (unsigned short*)(ws + off); off += (size_t)NBATCH * HID * 2;
    unsigned short* h1Lo  = (unsigned short*)(ws + off); off += (size_t)NBATCH * HID * 2;
    float* bsum           = (float*)(ws + off);          off += (size_t)4 * HID * 4;

    init_kernel<<<NBATCH, 256, 0, stream>>>(h0Hi, h0Lo);
    embed_kernel<<<SEQW * NBATCH / 4, 256, 0, stream>>>(qv, Wemb, embHi, embLo);
    convw_kernel<<<4 * HID, 256, 0, stream>>>(Wih, Whh, b_ih, b_hh, WHi, WLo, bsum);

    void* kargs[] = {
        (void*)&embHi, (void*)&embLo,
        (void*)&h0Hi, (void*)&h0Lo, (void*)&h1Hi, (void*)&h1Lo,
        (void*)&WHi, (void*)&WLo, (void*)&bsum, (void*)&out
    };
    hipLaunchCooperativeKernel((const void*)lstm_persist, dim3(256), dim3(512),
                               kargs, 0, stream);
}

// Round 4
// 1558.085 us; speedup vs baseline: 1.5989x; 1.5989x over previous
//
#include <hip/hip_runtime.h>
#include <hip/hip_bf16.h>

#define VOCAB 50000
#define EMBD  512
#define HID   1024
#define NB    256
#define SEQW  26
#define MTOT  (SEQW * NB)   /* 6656 */
#define NGATE (4 * HID)     /* 4096 */

typedef short short8 __attribute__((ext_vector_type(8)));
typedef float f32x4  __attribute__((ext_vector_type(4)));

__device__ __forceinline__ unsigned short f2bf_bits(float x) {
    union { __hip_bfloat16 b; unsigned short u; } cv;
    cv.b = __float2bfloat16(x);
    return cv.u;
}

__device__ __forceinline__ void split_bf16(float x, unsigned short& hi, unsigned short& lo) {
    __hip_bfloat16 h = __float2bfloat16(x);
    float hf = __bfloat162float(h);
    hi = f2bf_bits(x);
    lo = f2bf_bits(x - hf);
}

// ---------------- init: zero h0 (hi/lo) and c ----------------
__global__ void init_kernel(unsigned short* __restrict__ hHi0,
                            unsigned short* __restrict__ hLo0,
                            float* __restrict__ c) {
    int idx = blockIdx.x * blockDim.x + threadIdx.x; // 1024 x 256 = NB*HID
    hHi0[idx] = 0;
    hLo0[idx] = 0;
    c[idx] = 0.0f;
}

// ---------------- embedding: gather + tanh -> bf16 hi/lo ----------------
__global__ void embed_kernel(const int* __restrict__ qv,
                             const float* __restrict__ Wemb,
                             unsigned short* __restrict__ eHi,
                             unsigned short* __restrict__ eLo) {
    int pair = blockIdx.x * 4 + (threadIdx.x >> 6);
    int t = pair / NB;
    int b = pair % NB;
    int tok = qv[b * SEQW + t];
    int lane = threadIdx.x & 63;
    size_t base = (size_t)pair * EMBD;
    if (tok > 0) {
        int v = tok - 1;
        for (int e = lane; e < EMBD; e += 64) {
            float x = Wemb[(size_t)e * VOCAB + v];
            float y = tanhf(x);
            unsigned short hi, lo;
            split_bf16(y, hi, lo);
            eHi[base + e] = hi;
            eLo[base + e] = lo;
        }
    } else {
        for (int e = lane; e < EMBD; e += 64) {
            eHi[base + e] = 0;
            eLo[base + e] = 0;
        }
    }
}

// ---------------- weight split (separate ih / hh) + bias sum ----------------
__global__ void convw_kernel(const float* __restrict__ Wih,
                             const float* __restrict__ Whh,
                             const float* __restrict__ b_ih,
                             const float* __restrict__ b_hh,
                             unsigned short* __restrict__ ihHi,
                             unsigned short* __restrict__ ihLo,
                             unsigned short* __restrict__ hhHi,
                             unsigned short* __restrict__ hhLo,
                             float* __restrict__ bsum) {
    int j = blockIdx.x; // 0..4095
    if (threadIdx.x == 0) bsum[j] = b_ih[j] + b_hh[j];
    for (int col = threadIdx.x; col < EMBD; col += blockDim.x) {
        unsigned short hi, lo;
        split_bf16(Wih[(size_t)j * EMBD + col], hi, lo);
        ihHi[(size_t)j * EMBD + col] = hi;
        ihLo[(size_t)j * EMBD + col] = lo;
    }
    for (int col = threadIdx.x; col < HID; col += blockDim.x) {
        unsigned short hi, lo;
        split_bf16(Whh[(size_t)j * HID + col], hi, lo);
        hhHi[(size_t)j * HID + col] = hi;
        hhLo[(size_t)j * HID + col] = lo;
    }
}

// ---------------- pre-GEMM: G0[6656][4096] = emb @ Wih^T (3-term bf16) ------
// grid (32, 52): x = col tile (32 jh-cols x 4 gates = 128 cols), y = row tile (128 rows)
// 512 threads, 8 waves: wave = (gate g = w&3, mh = w>>2). Wave: 4 Mfrags x 2 Nfrags.
__global__ __launch_bounds__(512, 1) void pregemm_kernel(
    const unsigned short* __restrict__ eHi, const unsigned short* __restrict__ eLo,
    const unsigned short* __restrict__ ihHi, const unsigned short* __restrict__ ihLo,
    float* __restrict__ G0)
{
    int jh0 = blockIdx.x * 32;
    int m0  = blockIdx.y * 128;
    int wave = threadIdx.x >> 6;
    int g  = wave & 3;
    int mh = wave >> 2;
    int lane = threadIdx.x & 63;
    int col16 = lane & 15;
    int g4 = lane >> 4;

    f32x4 acc[4][2];
    #pragma unroll
    for (int fm = 0; fm < 4; ++fm)
        #pragma unroll
        for (int fn = 0; fn < 2; ++fn)
            acc[fm][fn] = (f32x4){0.f, 0.f, 0.f, 0.f};

    const unsigned short* aHiP[4];
    const unsigned short* aLoP[4];
    #pragma unroll
    for (int fm = 0; fm < 4; ++fm) {
        size_t row = (size_t)(m0 + mh * 64 + fm * 16 + col16);
        aHiP[fm] = eHi + row * EMBD + 8 * g4;
        aLoP[fm] = eLo + row * EMBD + 8 * g4;
    }
    const unsigned short* bHiP[2];
    const unsigned short* bLoP[2];
    #pragma unroll
    for (int fn = 0; fn < 2; ++fn) {
        size_t row = (size_t)(g * HID + jh0 + fn * 16 + col16);
        bHiP[fn] = ihHi + row * EMBD + 8 * g4;
        bLoP[fn] = ihLo + row * EMBD + 8 * g4;
    }

    #pragma unroll
    for (int kk = 0; kk < EMBD; kk += 32) {
        short8 bH[2], bL[2];
        #pragma unroll
        for (int fn = 0; fn < 2; ++fn) {
            bH[fn] = *(const short8*)(bHiP[fn] + kk);
            bL[fn] = *(const short8*)(bLoP[fn] + kk);
        }
        #pragma unroll
        for (int fm = 0; fm < 4; ++fm) {
            short8 aH = *(const short8*)(aHiP[fm] + kk);
            short8 aL = *(const short8*)(aLoP[fm] + kk);
            #pragma unroll
            for (int fn = 0; fn < 2; ++fn) {
                acc[fm][fn] = __builtin_amdgcn_mfma_f32_16x16x32_bf16(aH, bH[fn], acc[fm][fn], 0, 0, 0);
                acc[fm][fn] = __builtin_amdgcn_mfma_f32_16x16x32_bf16(aH, bL[fn], acc[fm][fn], 0, 0, 0);
                acc[fm][fn] = __builtin_amdgcn_mfma_f32_16x16x32_bf16(aL, bH[fn], acc[fm][fn], 0, 0, 0);
            }
        }
    }

    #pragma unroll
    for (int fm = 0; fm < 4; ++fm)
        #pragma unroll
        for (int fn = 0; fn < 2; ++fn)
            #pragma unroll
            for (int r = 0; r < 4; ++r) {
                int row = m0 + mh * 64 + fm * 16 + g4 * 4 + r;
                int col = g * HID + jh0 + fn * 16 + col16;
                G0[(size_t)row * NGATE + col] = acc[fm][fn][r];
            }
}

// ---------------- one LSTM step: gates_h = h @ Whh^T, fused epilogue --------
// grid 256 (1D): jt = (id&7)*8 + ((id>>3)&7) -> XCD = id%8 owns 8 jt tiles
//   (512 Whh rows x 1024 x 4B = 2.1MB) + A_h (1MB) = 3.1MB < 4MB L2, stable
//   across steps. mt = id>>6. 512 threads, 8 waves: (g = w&3, mh = w>>2),
//   wave = 2 Mfrags x 1 Nfrag over BM=64, BN=16 jh-cols x 4 gates.
__global__ __launch_bounds__(512, 1) void lstm_step_kernel(
    const unsigned short* __restrict__ hInHi, const unsigned short* __restrict__ hInLo,
    const unsigned short* __restrict__ hhHi,  const unsigned short* __restrict__ hhLo,
    const float* __restrict__ G0t,  // G0 + t*NB*NGATE
    const float* __restrict__ bsum,
    float* __restrict__ c,
    unsigned short* __restrict__ hOutHi, unsigned short* __restrict__ hOutLo,
    float* __restrict__ out, int is_last)
{
    int id = blockIdx.x;
    int jt = (id & 7) * 8 + ((id >> 3) & 7); // 0..63
    int mt = id >> 6;                        // 0..3
    int jh0 = jt * 16;
    int m0 = mt * 64;

    int tid = threadIdx.x;
    int wave = tid >> 6;
    int g  = wave & 3;
    int mh = wave >> 2;
    int lane = tid & 63;
    int col16 = lane & 15;
    int g4 = lane >> 4;

    int mA = m0 + mh * 32 + col16;
    const unsigned short* a0Hi = hInHi + (size_t)mA * HID + 8 * g4;
    const unsigned short* a0Lo = hInLo + (size_t)mA * HID + 8 * g4;
    const unsigned short* a1Hi = a0Hi + (size_t)16 * HID;
    const unsigned short* a1Lo = a0Lo + (size_t)16 * HID;

    int jB = g * HID + jh0 + col16;
    const unsigned short* bHi = hhHi + (size_t)jB * HID + 8 * g4;
    const unsigned short* bLo = hhLo + (size_t)jB * HID + 8 * g4;

    f32x4 acc0 = {0.f, 0.f, 0.f, 0.f};
    f32x4 acc1 = {0.f, 0.f, 0.f, 0.f};

    #pragma unroll
    for (int kk = 0; kk < HID; kk += 32) {
        short8 bH  = *(const short8*)(bHi + kk);
        short8 bL  = *(const short8*)(bLo + kk);
        short8 aH0 = *(const short8*)(a0Hi + kk);
        short8 aL0 = *(const short8*)(a0Lo + kk);
        short8 aH1 = *(const short8*)(a1Hi + kk);
        short8 aL1 = *(const short8*)(a1Lo + kk);
        acc0 = __builtin_amdgcn_mfma_f32_16x16x32_bf16(aH0, bH, acc0, 0, 0, 0);
        acc0 = __builtin_amdgcn_mfma_f32_16x16x32_bf16(aH0, bL, acc0, 0, 0, 0);
        acc0 = __builtin_amdgcn_mfma_f32_16x16x32_bf16(aL0, bH, acc0, 0, 0, 0);
        acc1 = __builtin_amdgcn_mfma_f32_16x16x32_bf16(aH1, bH, acc1, 0, 0, 0);
        acc1 = __builtin_amdgcn_mfma_f32_16x16x32_bf16(aH1, bL, acc1, 0, 0, 0);
        acc1 = __builtin_amdgcn_mfma_f32_16x16x32_bf16(aL1, bH, acc1, 0, 0, 0);
    }

    __shared__ float gbuf[4][64][16];
    #pragma unroll
    for (int r = 0; r < 4; ++r) {
        gbuf[g][mh * 32 +      g4 * 4 + r][col16] = acc0[r];
        gbuf[g][mh * 32 + 16 + g4 * 4 + r][col16] = acc1[r];
    }
    __syncthreads();

    #pragma unroll
    for (int u = 0; u < 2; ++u) {
        int idx = tid + u * 512;
        int ml = idx >> 4, nl = idx & 15;
        int b = m0 + ml, jh = jh0 + nl;
        size_t grow = (size_t)b * NGATE + jh;
        float gi  = gbuf[0][ml][nl] + G0t[grow]            + bsum[jh];
        float gf  = gbuf[1][ml][nl] + G0t[grow + HID]      + bsum[HID + jh];
        float gg_ = gbuf[2][ml][nl] + G0t[grow + 2 * HID]  + bsum[2 * HID + jh];
        float go  = gbuf[3][ml][nl] + G0t[grow + 3 * HID]  + bsum[3 * HID + jh];
        float si = 1.0f / (1.0f + expf(-gi));
        float sf = 1.0f / (1.0f + expf(-gf));
        float so = 1.0f / (1.0f + expf(-go));
        float tg = tanhf(gg_);
        size_t p = (size_t)b * HID + jh;
        float cN = sf * c[p] + si * tg;
        float hN = so * tanhf(cN);
        c[p] = cN;
        unsigned short hh, hl;
        split_bf16(hN, hh, hl);
        hOutHi[p] = hh;
        hOutLo[p] = hl;
        if (is_last) out[p] = hN;
    }
}

extern "C" void kernel_launch(void* const* d_in, const int* in_sizes, int n_in,
                              void* d_out, int out_size, void* d_ws, size_t ws_size,
                              hipStream_t stream) {
    const int*   qv   = (const int*)d_in[0];
    const float* Wemb = (const float*)d_in[2];
    const float* Wih  = (const float*)d_in[3];
    const float* Whh  = (const float*)d_in[4];
    const float* b_ih = (const float*)d_in[5];
    const float* b_hh = (const float*)d_in[6];
    float* out = (float*)d_out;

    char* ws = (char*)d_ws;
    size_t off = 0;
    unsigned short* embHi = (unsigned short*)(ws + off); off += (size_t)MTOT * EMBD * 2;
    unsigned short* embLo = (unsigned short*)(ws + off); off += (size_t)MTOT * EMBD * 2;
    unsigned short* ihHi  = (unsigned short*)(ws + off); off += (size_t)NGATE * EMBD * 2;
    unsigned short* ihLo  = (unsigned short*)(ws + off); off += (size_t)NGATE * EMBD * 2;
    unsigned short* hhHi  = (unsigned short*)(ws + off); off += (size_t)NGATE * HID * 2;
    unsigned short* hhLo  = (unsigned short*)(ws + off); off += (size_t)NGATE * HID * 2;
    unsigned short* h0Hi  = (unsigned short*)(ws + off); off += (size_t)NB * HID * 2;
    unsigned short* h0Lo  = (unsigned short*)(ws + off); off += (size_t)NB * HID * 2;
    unsigned short* h1Hi  = (unsigned short*)(ws + off); off += (size_t)NB * HID * 2;
    unsigned short* h1Lo  = (unsigned short*)(ws + off); off += (size_t)NB * HID * 2;
    float* c              = (float*)(ws + off);          off += (size_t)NB * HID * 4;
    float* bsum           = (float*)(ws + off);          off += (size_t)NGATE * 4;
    float* G0             = (float*)(ws + off);          off += (size_t)MTOT * NGATE * 4; // 109 MB

    init_kernel<<<NB * HID / 256, 256, 0, stream>>>(h0Hi, h0Lo, c);
    embed_kernel<<<MTOT / 4, 256, 0, stream>>>(qv, Wemb, embHi, embLo);
    convw_kernel<<<NGATE, 256, 0, stream>>>(Wih, Whh, b_ih, b_hh,
                                            ihHi, ihLo, hhHi, hhLo, bsum);
    pregemm_kernel<<<dim3(32, 52), 512, 0, stream>>>(embHi, embLo, ihHi, ihLo, G0);

    for (int t = 0; t < SEQW; ++t) {
        const unsigned short* hInHi  = (t & 1) ? h1Hi : h0Hi;
        const unsigned short* hInLo  = (t & 1) ? h1Lo : h0Lo;
        unsigned short*       hOutHi = (t & 1) ? h0Hi : h1Hi;
        unsigned short*       hOutLo = (t & 1) ? h0Lo : h1Lo;
        lstm_step_kernel<<<256, 512, 0, stream>>>(
            hInHi, hInLo, hhHi, hhLo,
            G0 + (size_t)t * NB * NGATE, bsum, c,
            hOutHi, hOutLo, out, (t == SEQW - 1) ? 1 : 0);
    }
}